// Round 3
// baseline (4292.165 us; speedup 1.0000x reference)
//
#include <hip/hip_runtime.h>
#include <stdint.h>

#define F 128
#define PROP_GRID 1024     // 4 blocks/CU on 256 CUs, guaranteed by launch_bounds(256,4)
#define PROP_BLOCK 256
#define MAX_SLOTS 4        // nodes per wave slots: covers N up to 4*4096 = 16384

struct EdgeRec { int src; float norm; };

// ---- 1. in-degree histogram over col ----
__global__ void deg_kernel(const int* __restrict__ col, int* __restrict__ deg, int E) {
    int e = blockIdx.x * blockDim.x + threadIdx.x;
    if (e < E) atomicAdd(&deg[col[e]], 1);
}

// ---- 2. deg^{-1/2} with zero-degree -> 1 ----
__global__ void dinv_kernel(const int* __restrict__ deg, float* __restrict__ dinv, int N) {
    int n = blockIdx.x * blockDim.x + threadIdx.x;
    if (n < N) {
        int d = deg[n];
        if (d < 1) d = 1;
        dinv[n] = rsqrtf((float)d);
    }
}

// ---- 3. exclusive scan of deg -> start[0..N], single block (round-1 proven) ----
__global__ void scan_kernel(const int* __restrict__ deg, int* __restrict__ start, int N) {
    __shared__ int sm[1024];
    __shared__ int carry_s;
    int tid = threadIdx.x;
    if (tid == 0) carry_s = 0;
    __syncthreads();
    for (int base = 0; base < N; base += 1024) {
        int i = base + tid;
        int v = (i < N) ? deg[i] : 0;
        int val = v;
        sm[tid] = val;
        __syncthreads();
        for (int off = 1; off < 1024; off <<= 1) {
            int t = 0;
            if (tid >= off) t = sm[tid - off];
            __syncthreads();
            val += t;
            sm[tid] = val;
            __syncthreads();
        }
        int carry = carry_s;
        if (i < N) start[i] = carry + val - v;   // exclusive
        __syncthreads();
        if (tid == 1023) carry_s = carry + val;
        __syncthreads();
    }
    if (tid == 0) start[N] = carry_s;
}

// ---- 4. counting-sort edges by target node; fuse norm computation ----
__global__ void bucket_kernel(const int* __restrict__ row, const int* __restrict__ col,
                              const float* __restrict__ dinv, const int* __restrict__ start,
                              int* __restrict__ cursor, EdgeRec* __restrict__ edges, int E) {
    int e = blockIdx.x * blockDim.x + threadIdx.x;
    if (e < E) {
        int c = col[e];
        int r = row[e];
        int pos = start[c] + atomicAdd(&cursor[c], 1);
        EdgeRec rec;
        rec.src  = r;
        rec.norm = dinv[r] * dinv[c];
        edges[pos] = rec;
    }
}

// ---- device-scope grid barrier (one fresh counter per use; no reuse) ----
__device__ __forceinline__ void grid_barrier(int* ctr, int nblocks) {
    __threadfence();          // agent-scope release: each thread flushes its stores
    __syncthreads();          // whole block's stores are now fenced
    if (threadIdx.x == 0) {
        __hip_atomic_fetch_add(ctr, 1, __ATOMIC_ACQ_REL, __HIP_MEMORY_SCOPE_AGENT);
        int spins = 0;
        while (__hip_atomic_load(ctr, __ATOMIC_ACQUIRE, __HIP_MEMORY_SCOPE_AGENT) < nblocks) {
            __builtin_amdgcn_s_sleep(2);
            if (++spins > (1 << 26)) break;   // bail out instead of hanging the harness
        }
    }
    __syncthreads();          // everyone waits on tid0's acquire
    __threadfence();          // acquire: invalidate stale L1 before re-reading cur
}

// ---- 5. ALL layers fused: persistent kernel, manual barrier between layers ----
__global__ __launch_bounds__(PROP_BLOCK, 4) void prop_kernel(
        const float* __restrict__ x, float* __restrict__ cur0, float* __restrict__ cur1,
        float* __restrict__ h, const int* __restrict__ start,
        const EdgeRec* __restrict__ edges, const float* __restrict__ kv,
        const float* __restrict__ wt, int* __restrict__ bar, int N, int L, int nblocks) {
    const int wave = (blockIdx.x * blockDim.x + threadIdx.x) >> 6;
    const int lane = threadIdx.x & 63;
    const int W = (gridDim.x * blockDim.x) >> 6;   // total waves

    float2 creg[MAX_SLOTS], upd[MAX_SLOTS];
#pragma unroll
    for (int sl = 0; sl < MAX_SLOTS; ++sl) {
        int node = wave + sl * W;
        upd[sl] = make_float2(0.f, 0.f);
        if (node < N)
            creg[sl] = ((const float2*)(x + (size_t)node * F))[lane];
    }

    for (int l = 0; l < L; ++l) {
        float tk = tanhf(kv[l]);
        const float* cin = (l == 0) ? x : ((l & 1) ? cur0 : cur1);
        float* cout = (l & 1) ? cur1 : cur0;
#pragma unroll
        for (int sl = 0; sl < MAX_SLOTS; ++sl) {
            int node = wave + sl * W;
            if (node < N) {
                int s = start[node], t = start[node + 1];
                float2 acc = make_float2(0.f, 0.f);
                EdgeRec r0;
                if (s < t) r0 = edges[s];
                for (int e = s; e < t; ++e) {
                    EdgeRec rn = r0;
                    if (e + 1 < t) rn = edges[e + 1];   // prefetch next record
                    float2 v = ((const float2*)(cin + (size_t)r0.src * F))[lane];
                    acc.x += r0.norm * v.x;
                    acc.y += r0.norm * v.y;
                    r0 = rn;
                }
                float2 nc = make_float2(creg[sl].x - acc.x, creg[sl].y - acc.y);
                ((float2*)(cout + (size_t)node * F))[lane] = nc;
                upd[sl].x += tk * nc.x;
                upd[sl].y += tk * nc.y;
                creg[sl] = nc;
            }
        }
        grid_barrier(&bar[l], nblocks);
    }

    float c  = 1.f / (1.f + __expf(-wt[0]));
    float c1 = 1.f - c;
#pragma unroll
    for (int sl = 0; sl < MAX_SLOTS; ++sl) {
        int node = wave + sl * W;
        if (node < N) {
            float2 xv = ((const float2*)(x + (size_t)node * F))[lane];
            float2 hv = make_float2(c * upd[sl].x + c1 * xv.x,
                                    c * upd[sl].y + c1 * xv.y);
            ((float2*)(h + (size_t)node * F))[lane] = hv;
        }
    }
}

// ---- 6. epilogue GEMM: out = relu(h @ W^T + b) ----
#define TM 32
#define KC 32
__global__ __launch_bounds__(256) void final_kernel(
        const float* __restrict__ h, const float* __restrict__ W,
        const float* __restrict__ bias, float* __restrict__ out, int N) {
    __shared__ float hs[TM * F];       // 16 KB
    __shared__ float Wl[KC * 129];     // padded stride kills bank conflicts
    int tid  = threadIdx.x;
    int row0 = blockIdx.x * TM;
    for (int j = tid; j < TM * F; j += 256) {
        int r = j >> 7, k = j & 127;
        int gr = row0 + r;
        hs[j] = (gr < N) ? h[(size_t)gr * F + k] : 0.f;
    }
    int c  = tid & 127;
    int rg = tid >> 7;
    float acc[16];
#pragma unroll
    for (int i = 0; i < 16; ++i) acc[i] = 0.f;
    for (int kc = 0; kc < F; kc += KC) {
        __syncthreads();
        for (int j = tid; j < KC * F; j += 256) {
            int c2 = j >> 5, kk = j & 31;
            Wl[kk * 129 + c2] = W[(size_t)c2 * F + kc + kk];
        }
        __syncthreads();
#pragma unroll 8
        for (int kk = 0; kk < KC; ++kk) {
            float w = Wl[kk * 129 + c];
#pragma unroll
            for (int r = 0; r < 16; ++r)
                acc[r] += hs[(rg * 16 + r) * F + kc + kk] * w;
        }
    }
    float bv = bias[c];
#pragma unroll
    for (int r = 0; r < 16; ++r) {
        int gr = row0 + rg * 16 + r;
        if (gr < N) {
            float v = acc[r] + bv;
            out[(size_t)gr * F + c] = v > 0.f ? v : 0.f;
        }
    }
}

extern "C" void kernel_launch(void* const* d_in, const int* in_sizes, int n_in,
                              void* d_out, int out_size, void* d_ws, size_t ws_size,
                              hipStream_t stream) {
    const float* x   = (const float*)d_in[0];
    const int*   ei  = (const int*)d_in[1];
    const float* kv  = (const float*)d_in[2];
    const float* wt  = (const float*)d_in[3];
    const float* W   = (const float*)d_in[4];
    const float* b   = (const float*)d_in[5];
    float* out = (float*)d_out;

    const int E = in_sizes[1] / 2;
    const int N = in_sizes[0] / F;
    const int L = in_sizes[2];
    const int* row = ei;           // edge_index[0]
    const int* col = ei + E;       // edge_index[1]

    size_t off = 0;
    auto alloc = [&](size_t bytes) {
        void* p = (char*)d_ws + off;
        off += (bytes + 255) & ~(size_t)255;
        return p;
    };
    int*     deg    = (int*)alloc((size_t)N * 4);
    int*     cursor = (int*)alloc((size_t)N * 4);
    int*     startp = (int*)alloc((size_t)(N + 1) * 4);
    float*   dinv   = (float*)alloc((size_t)N * 4);
    int*     bar    = (int*)alloc((size_t)(L > 16 ? L : 16) * 4);
    EdgeRec* edges  = (EdgeRec*)alloc((size_t)E * sizeof(EdgeRec));
    float*   cur0   = (float*)alloc((size_t)N * F * 4);
    float*   cur1   = (float*)alloc((size_t)N * F * 4);
    float*   h      = (float*)alloc((size_t)N * F * 4);
    (void)ws_size;

    hipMemsetAsync(deg,    0, (size_t)N * 4, stream);
    hipMemsetAsync(cursor, 0, (size_t)N * 4, stream);
    hipMemsetAsync(bar,    0, (size_t)(L > 16 ? L : 16) * 4, stream);

    deg_kernel<<<(E + 255) / 256, 256, 0, stream>>>(col, deg, E);
    dinv_kernel<<<(N + 255) / 256, 256, 0, stream>>>(deg, dinv, N);
    scan_kernel<<<1, 1024, 0, stream>>>(deg, startp, N);
    bucket_kernel<<<(E + 255) / 256, 256, 0, stream>>>(row, col, dinv, startp, cursor, edges, E);

    prop_kernel<<<PROP_GRID, PROP_BLOCK, 0, stream>>>(
        x, cur0, cur1, h, startp, edges, kv, wt, bar, N, L, PROP_GRID);

    final_kernel<<<(N + TM - 1) / TM, 256, 0, stream>>>(h, W, b, out, N);
}

// Round 4
// 329.095 us; speedup vs baseline: 13.0423x; 13.0423x over previous
//
#include <hip/hip_runtime.h>
#include <stdint.h>

#define F 128

struct EdgeRec { int src; float norm; };

__device__ __forceinline__ int rl_i(int v, int l) {
    return __builtin_amdgcn_readlane(v, l);
}
__device__ __forceinline__ float rl_f(float v, int l) {
    return __int_as_float(__builtin_amdgcn_readlane(__float_as_int(v), l));
}

// ---- 1. in-degree histogram over col ----
__global__ void deg_kernel(const int* __restrict__ col, int* __restrict__ deg, int E) {
    int e = blockIdx.x * blockDim.x + threadIdx.x;
    if (e < E) atomicAdd(&deg[col[e]], 1);
}

// ---- 2. exclusive scan of deg -> start[0..N]  (round-1 proven) ----
__global__ void scan_kernel(const int* __restrict__ deg, int* __restrict__ start, int N) {
    __shared__ int sm[1024];
    __shared__ int carry_s;
    int tid = threadIdx.x;
    if (tid == 0) carry_s = 0;
    __syncthreads();
    for (int base = 0; base < N; base += 1024) {
        int i = base + tid;
        int v = (i < N) ? deg[i] : 0;
        int val = v;
        sm[tid] = val;
        __syncthreads();
        for (int off = 1; off < 1024; off <<= 1) {
            int t = 0;
            if (tid >= off) t = sm[tid - off];
            __syncthreads();
            val += t;
            sm[tid] = val;
            __syncthreads();
        }
        int carry = carry_s;
        if (i < N) start[i] = carry + val - v;   // exclusive
        __syncthreads();
        if (tid == 1023) carry_s = carry + val;
        __syncthreads();
    }
    if (tid == 0) start[N] = carry_s;
}

// ---- 3. counting-sort edges by target; norm = rsqrt(deg[r])*rsqrt(deg[c]) fused ----
__global__ void bucket_kernel(const int* __restrict__ row, const int* __restrict__ col,
                              const int* __restrict__ deg, const int* __restrict__ start,
                              int* __restrict__ cursor, EdgeRec* __restrict__ edges, int E) {
    int e = blockIdx.x * blockDim.x + threadIdx.x;
    if (e < E) {
        int c = col[e];
        int r = row[e];
        int pos = start[c] + atomicAdd(&cursor[c], 1);
        int dr = deg[r]; if (dr < 1) dr = 1;
        int dc = deg[c]; if (dc < 1) dc = 1;
        EdgeRec rec;
        rec.src  = r;
        rec.norm = rsqrtf((float)dr) * rsqrtf((float)dc);
        edges[pos] = rec;
    }
}

// ---- 4. one layer: wave per node; 64-record lane staging + readlane broadcast,
//          8 independent gathers in flight ----
__global__ __launch_bounds__(256) void layer_kernel(
        const float* __restrict__ cin, float* __restrict__ cout,
        float* __restrict__ upd, const int* __restrict__ start,
        const EdgeRec* __restrict__ edges, const float* __restrict__ kv,
        int layer, int first, int N) {
    int node = (blockIdx.x * blockDim.x + threadIdx.x) >> 6;
    int lane = threadIdx.x & 63;
    if (node >= N) return;
    float tk = tanhf(kv[layer]);
    int s = start[node], t = start[node + 1];

    float2 a0{0,0}, a1{0,0}, a2{0,0}, a3{0,0}, a4{0,0}, a5{0,0}, a6{0,0}, a7{0,0};
    for (int base = s; base < t; base += 64) {
        int cnt = t - base; if (cnt > 64) cnt = 64;
        EdgeRec rec = edges[base + (lane < cnt ? lane : 0)];  // coalesced 8B/lane staging
        int j = 0;
        for (; j + 8 <= cnt; j += 8) {
            int   s0 = rl_i(rec.src, j+0), s1 = rl_i(rec.src, j+1);
            int   s2 = rl_i(rec.src, j+2), s3 = rl_i(rec.src, j+3);
            int   s4 = rl_i(rec.src, j+4), s5 = rl_i(rec.src, j+5);
            int   s6 = rl_i(rec.src, j+6), s7 = rl_i(rec.src, j+7);
            float n0 = rl_f(rec.norm, j+0), n1 = rl_f(rec.norm, j+1);
            float n2 = rl_f(rec.norm, j+2), n3 = rl_f(rec.norm, j+3);
            float n4 = rl_f(rec.norm, j+4), n5 = rl_f(rec.norm, j+5);
            float n6 = rl_f(rec.norm, j+6), n7 = rl_f(rec.norm, j+7);
            float2 v0 = ((const float2*)(cin + (size_t)s0 * F))[lane];
            float2 v1 = ((const float2*)(cin + (size_t)s1 * F))[lane];
            float2 v2 = ((const float2*)(cin + (size_t)s2 * F))[lane];
            float2 v3 = ((const float2*)(cin + (size_t)s3 * F))[lane];
            float2 v4 = ((const float2*)(cin + (size_t)s4 * F))[lane];
            float2 v5 = ((const float2*)(cin + (size_t)s5 * F))[lane];
            float2 v6 = ((const float2*)(cin + (size_t)s6 * F))[lane];
            float2 v7 = ((const float2*)(cin + (size_t)s7 * F))[lane];
            a0.x += n0*v0.x; a0.y += n0*v0.y;
            a1.x += n1*v1.x; a1.y += n1*v1.y;
            a2.x += n2*v2.x; a2.y += n2*v2.y;
            a3.x += n3*v3.x; a3.y += n3*v3.y;
            a4.x += n4*v4.x; a4.y += n4*v4.y;
            a5.x += n5*v5.x; a5.y += n5*v5.y;
            a6.x += n6*v6.x; a6.y += n6*v6.y;
            a7.x += n7*v7.x; a7.y += n7*v7.y;
        }
        for (; j < cnt; ++j) {
            int   sj = rl_i(rec.src, j);
            float nj = rl_f(rec.norm, j);
            float2 v = ((const float2*)(cin + (size_t)sj * F))[lane];
            a0.x += nj*v.x; a0.y += nj*v.y;
        }
    }
    float2 acc = make_float2(((a0.x+a1.x)+(a2.x+a3.x)) + ((a4.x+a5.x)+(a6.x+a7.x)),
                             ((a0.y+a1.y)+(a2.y+a3.y)) + ((a4.y+a5.y)+(a6.y+a7.y)));

    float2 c = ((const float2*)(cin + (size_t)node * F))[lane];
    float2 nc = make_float2(c.x - acc.x, c.y - acc.y);
    ((float2*)(cout + (size_t)node * F))[lane] = nc;
    float2* up = (float2*)(upd + (size_t)node * F);
    if (first) {
        up[lane] = make_float2(tk * nc.x, tk * nc.y);   // no memset needed
    } else {
        float2 u = up[lane];
        u.x += tk * nc.x;
        u.y += tk * nc.y;
        up[lane] = u;
    }
}

// ---- 5. epilogue: h = c*update + (1-c)*x; out = relu(h @ W^T + b) ----
#define TM 32
#define KC 32
__global__ __launch_bounds__(256) void final_kernel(
        const float* __restrict__ x, const float* __restrict__ update,
        const float* __restrict__ W, const float* __restrict__ bias,
        const float* __restrict__ wt, float* __restrict__ out, int N) {
    __shared__ float hs[TM * F];       // 16 KB
    __shared__ float Wl[KC * 129];     // padded stride kills bank conflicts
    int tid  = threadIdx.x;
    int row0 = blockIdx.x * TM;
    float cst  = 1.f / (1.f + __expf(-wt[0]));
    float cst1 = 1.f - cst;
    for (int j = tid; j < TM * F; j += 256) {
        int r = j >> 7, k = j & 127;
        int gr = row0 + r;
        float v = 0.f;
        if (gr < N) {
            size_t idx = (size_t)gr * F + k;
            v = cst * update[idx] + cst1 * x[idx];
        }
        hs[j] = v;
    }
    int c  = tid & 127;
    int rg = tid >> 7;
    float acc[16];
#pragma unroll
    for (int i = 0; i < 16; ++i) acc[i] = 0.f;
    for (int kc = 0; kc < F; kc += KC) {
        __syncthreads();
        for (int j = tid; j < KC * F; j += 256) {
            int c2 = j >> 5, kk = j & 31;
            Wl[kk * 129 + c2] = W[(size_t)c2 * F + kc + kk];
        }
        __syncthreads();
#pragma unroll 8
        for (int kk = 0; kk < KC; ++kk) {
            float w = Wl[kk * 129 + c];
#pragma unroll
            for (int r = 0; r < 16; ++r)
                acc[r] += hs[(rg * 16 + r) * F + kc + kk] * w;
        }
    }
    float bv = bias[c];
#pragma unroll
    for (int r = 0; r < 16; ++r) {
        int gr = row0 + rg * 16 + r;
        if (gr < N) {
            float v = acc[r] + bv;
            out[(size_t)gr * F + c] = v > 0.f ? v : 0.f;
        }
    }
}

extern "C" void kernel_launch(void* const* d_in, const int* in_sizes, int n_in,
                              void* d_out, int out_size, void* d_ws, size_t ws_size,
                              hipStream_t stream) {
    const float* x   = (const float*)d_in[0];
    const int*   ei  = (const int*)d_in[1];
    const float* kv  = (const float*)d_in[2];
    const float* wt  = (const float*)d_in[3];
    const float* W   = (const float*)d_in[4];
    const float* b   = (const float*)d_in[5];
    float* out = (float*)d_out;

    const int E = in_sizes[1] / 2;
    const int N = in_sizes[0] / F;
    const int L = in_sizes[2];
    const int* row = ei;           // edge_index[0]
    const int* col = ei + E;       // edge_index[1]

    size_t off = 0;
    auto alloc = [&](size_t bytes) {
        void* p = (char*)d_ws + off;
        off += (bytes + 255) & ~(size_t)255;
        return p;
    };
    int*     degcur = (int*)alloc((size_t)2 * N * 4);   // deg | cursor, one memset
    int*     deg    = degcur;
    int*     cursor = degcur + N;
    int*     startp = (int*)alloc((size_t)(N + 1) * 4);
    EdgeRec* edges  = (EdgeRec*)alloc((size_t)E * sizeof(EdgeRec));
    float*   cur0   = (float*)alloc((size_t)N * F * 4);
    float*   cur1   = (float*)alloc((size_t)N * F * 4);
    float*   update = (float*)alloc((size_t)N * F * 4);
    (void)ws_size;

    hipMemsetAsync(degcur, 0, (size_t)2 * N * 4, stream);

    deg_kernel<<<(E + 255) / 256, 256, 0, stream>>>(col, deg, E);
    scan_kernel<<<1, 1024, 0, stream>>>(deg, startp, N);
    bucket_kernel<<<(E + 255) / 256, 256, 0, stream>>>(row, col, deg, startp, cursor, edges, E);

    float* bufs[2] = {cur0, cur1};
    for (int l = 0; l < L; ++l) {
        const float* cin = (l == 0) ? x : bufs[(l - 1) & 1];
        float* cout = bufs[l & 1];
        layer_kernel<<<(N * 64 + 255) / 256, 256, 0, stream>>>(
            cin, cout, update, startp, edges, kv, l, (l == 0) ? 1 : 0, N);
    }

    final_kernel<<<(N + TM - 1) / TM, 256, 0, stream>>>(x, update, W, b, wt, out, N);
}

// Round 5
// 297.224 us; speedup vs baseline: 14.4408x; 1.1072x over previous
//
#include <hip/hip_runtime.h>
#include <stdint.h>

#define F 128
#define NREP 8          // cursor/histogram replicas (contention /8)
#define EPT 4           // edges per thread in histogram/bucket

struct EdgeRec { int src; float norm; };

// ---- 1. replicated in-degree histogram over col ----
__global__ void deg_kernel(const int* __restrict__ col, int* __restrict__ hist,
                           int E, int N) {
    int rep = blockIdx.x & (NREP - 1);
    int e0 = (blockIdx.x * blockDim.x + threadIdx.x) * EPT;
    int* h = hist + (size_t)rep * N;
#pragma unroll
    for (int u = 0; u < EPT; ++u) {
        int e = e0 + u;
        if (e < E) atomicAdd(&h[col[e]], 1);
    }
}

// ---- 2. degc = sum over replicas; dinv = rsqrt(max(deg,1)) ----
__global__ void sumdinv_kernel(const int* __restrict__ hist, int* __restrict__ degc,
                               float* __restrict__ dinv, int N) {
    int n = blockIdx.x * blockDim.x + threadIdx.x;
    if (n < N) {
        int d = 0;
#pragma unroll
        for (int r = 0; r < NREP; ++r) d += hist[(size_t)r * N + n];
        degc[n] = d;
        if (d < 1) d = 1;
        dinv[n] = rsqrtf((float)d);
    }
}

// ---- 3. exclusive scan of degc -> start[0..N]  (proven) ----
__global__ void scan_kernel(const int* __restrict__ deg, int* __restrict__ start, int N) {
    __shared__ int sm[1024];
    __shared__ int carry_s;
    int tid = threadIdx.x;
    if (tid == 0) carry_s = 0;
    __syncthreads();
    for (int base = 0; base < N; base += 1024) {
        int i = base + tid;
        int v = (i < N) ? deg[i] : 0;
        int val = v;
        sm[tid] = val;
        __syncthreads();
        for (int off = 1; off < 1024; off <<= 1) {
            int t = 0;
            if (tid >= off) t = sm[tid - off];
            __syncthreads();
            val += t;
            sm[tid] = val;
            __syncthreads();
        }
        int carry = carry_s;
        if (i < N) start[i] = carry + val - v;   // exclusive
        __syncthreads();
        if (tid == 1023) carry_s = carry + val;
        __syncthreads();
    }
    if (tid == 0) start[N] = carry_s;
}

// ---- 4. seed cursor[r][c] = start[c] + prefix_r(hist[.][c]) ----
__global__ void seed_kernel(const int* __restrict__ hist, const int* __restrict__ start,
                            int* __restrict__ cursor, int N) {
    int n = blockIdx.x * blockDim.x + threadIdx.x;
    if (n < N) {
        int run = start[n];
#pragma unroll
        for (int r = 0; r < NREP; ++r) {
            cursor[(size_t)r * N + n] = run;
            run += hist[(size_t)r * N + n];
        }
    }
}

// ---- 5. bucket scatter with pre-seeded replicated cursors ----
// MUST use the same grid geometry + rep mapping as deg_kernel.
__global__ void bucket_kernel(const int* __restrict__ row, const int* __restrict__ col,
                              const float* __restrict__ dinv,
                              int* __restrict__ cursor, EdgeRec* __restrict__ edges,
                              int E, int N) {
    int rep = blockIdx.x & (NREP - 1);
    int e0 = (blockIdx.x * blockDim.x + threadIdx.x) * EPT;
    int* cur = cursor + (size_t)rep * N;
    int cs[EPT], rs[EPT], pos[EPT];
    float nm[EPT];
#pragma unroll
    for (int u = 0; u < EPT; ++u) {
        int e = e0 + u;
        if (e < E) { cs[u] = col[e]; rs[u] = row[e]; }
    }
#pragma unroll
    for (int u = 0; u < EPT; ++u) {
        int e = e0 + u;
        if (e < E) {
            nm[u]  = dinv[rs[u]] * dinv[cs[u]];
            pos[u] = atomicAdd(&cur[cs[u]], 1);
        }
    }
#pragma unroll
    for (int u = 0; u < EPT; ++u) {
        int e = e0 + u;
        if (e < E) {
            EdgeRec rec; rec.src = rs[u]; rec.norm = nm[u];
            edges[pos[u]] = rec;
        }
    }
}

// ---- 6. one layer: wave per node, half-wave float4 gathers ----
// lanes 0-31 handle even staged edges, 32-63 odd; each lane covers cols 4*li..4*li+3.
__global__ __launch_bounds__(256) void layer_kernel(
        const float* __restrict__ cin, float* __restrict__ cout,
        float* __restrict__ upd, const int* __restrict__ start,
        const EdgeRec* __restrict__ edges, const float* __restrict__ kv,
        int layer, int first, int N) {
    int node = (blockIdx.x * blockDim.x + threadIdx.x) >> 6;
    int lane = threadIdx.x & 63;
    if (node >= N) return;
    int half = lane >> 5;
    int li   = lane & 31;
    float tk = tanhf(kv[layer]);
    int s = start[node], t = start[node + 1];

    float4 a[8];
#pragma unroll
    for (int u = 0; u < 8; ++u) a[u] = make_float4(0.f, 0.f, 0.f, 0.f);

    for (int base = s; base < t; base += 64) {
        int cnt = t - base; if (cnt > 64) cnt = 64;
        EdgeRec rec = edges[base + (lane < cnt ? lane : 0)];  // coalesced staging
        int j = 0;
        for (; j + 16 <= cnt; j += 16) {
#pragma unroll
            for (int u = 0; u < 8; ++u) {
                int idx = j + 2 * u + half;
                int   s_ = __shfl(rec.src,  idx, 64);
                float n_ = __shfl(rec.norm, idx, 64);
                float4 v = ((const float4*)(cin + (size_t)s_ * F))[li];
                a[u].x += n_ * v.x; a[u].y += n_ * v.y;
                a[u].z += n_ * v.z; a[u].w += n_ * v.w;
            }
        }
        for (; j < cnt; j += 2) {
            int idx = j + half;
            int ic  = idx < cnt ? idx : j;
            int   s_ = __shfl(rec.src,  ic, 64);
            float n_ = __shfl(rec.norm, ic, 64);
            if (idx >= cnt) n_ = 0.f;
            float4 v = ((const float4*)(cin + (size_t)s_ * F))[li];
            a[0].x += n_ * v.x; a[0].y += n_ * v.y;
            a[0].z += n_ * v.z; a[0].w += n_ * v.w;
        }
    }
    float4 acc;
    acc.x = ((a[0].x+a[1].x)+(a[2].x+a[3].x)) + ((a[4].x+a[5].x)+(a[6].x+a[7].x));
    acc.y = ((a[0].y+a[1].y)+(a[2].y+a[3].y)) + ((a[4].y+a[5].y)+(a[6].y+a[7].y));
    acc.z = ((a[0].z+a[1].z)+(a[2].z+a[3].z)) + ((a[4].z+a[5].z)+(a[6].z+a[7].z));
    acc.w = ((a[0].w+a[1].w)+(a[2].w+a[3].w)) + ((a[4].w+a[5].w)+(a[6].w+a[7].w));
    // combine even/odd halves (lanes i and i+32 hold the same columns)
    acc.x += __shfl_xor(acc.x, 32, 64);
    acc.y += __shfl_xor(acc.y, 32, 64);
    acc.z += __shfl_xor(acc.z, 32, 64);
    acc.w += __shfl_xor(acc.w, 32, 64);

    if (half == 0) {
        float4 c = ((const float4*)(cin + (size_t)node * F))[li];
        float4 nc = make_float4(c.x - acc.x, c.y - acc.y, c.z - acc.z, c.w - acc.w);
        ((float4*)(cout + (size_t)node * F))[li] = nc;
        float4* up = (float4*)(upd + (size_t)node * F);
        if (first) {
            up[li] = make_float4(tk * nc.x, tk * nc.y, tk * nc.z, tk * nc.w);
        } else {
            float4 u4 = up[li];
            u4.x += tk * nc.x; u4.y += tk * nc.y;
            u4.z += tk * nc.z; u4.w += tk * nc.w;
            up[li] = u4;
        }
    }
}

// ---- 7. epilogue: h = c*update + (1-c)*x; out = relu(h @ W^T + b) ----
#define TM 32
#define KC 32
__global__ __launch_bounds__(256) void final_kernel(
        const float* __restrict__ x, const float* __restrict__ update,
        const float* __restrict__ W, const float* __restrict__ bias,
        const float* __restrict__ wt, float* __restrict__ out, int N) {
    __shared__ float hs[TM * F];
    __shared__ float Wl[KC * 129];
    int tid  = threadIdx.x;
    int row0 = blockIdx.x * TM;
    float cst  = 1.f / (1.f + __expf(-wt[0]));
    float cst1 = 1.f - cst;
    for (int j = tid; j < TM * F; j += 256) {
        int r = j >> 7, k = j & 127;
        int gr = row0 + r;
        float v = 0.f;
        if (gr < N) {
            size_t idx = (size_t)gr * F + k;
            v = cst * update[idx] + cst1 * x[idx];
        }
        hs[j] = v;
    }
    int c  = tid & 127;
    int rg = tid >> 7;
    float acc[16];
#pragma unroll
    for (int i = 0; i < 16; ++i) acc[i] = 0.f;
    for (int kc = 0; kc < F; kc += KC) {
        __syncthreads();
        for (int j = tid; j < KC * F; j += 256) {
            int c2 = j >> 5, kk = j & 31;
            Wl[kk * 129 + c2] = W[(size_t)c2 * F + kc + kk];
        }
        __syncthreads();
#pragma unroll 8
        for (int kk = 0; kk < KC; ++kk) {
            float w = Wl[kk * 129 + c];
#pragma unroll
            for (int r = 0; r < 16; ++r)
                acc[r] += hs[(rg * 16 + r) * F + kc + kk] * w;
        }
    }
    float bv = bias[c];
#pragma unroll
    for (int r = 0; r < 16; ++r) {
        int gr = row0 + rg * 16 + r;
        if (gr < N) {
            float v = acc[r] + bv;
            out[(size_t)gr * F + c] = v > 0.f ? v : 0.f;
        }
    }
}

extern "C" void kernel_launch(void* const* d_in, const int* in_sizes, int n_in,
                              void* d_out, int out_size, void* d_ws, size_t ws_size,
                              hipStream_t stream) {
    const float* x   = (const float*)d_in[0];
    const int*   ei  = (const int*)d_in[1];
    const float* kv  = (const float*)d_in[2];
    const float* wt  = (const float*)d_in[3];
    const float* W   = (const float*)d_in[4];
    const float* b   = (const float*)d_in[5];
    float* out = (float*)d_out;

    const int E = in_sizes[1] / 2;
    const int N = in_sizes[0] / F;
    const int L = in_sizes[2];
    const int* row = ei;           // edge_index[0]
    const int* col = ei + E;       // edge_index[1]

    size_t off = 0;
    auto alloc = [&](size_t bytes) {
        void* p = (char*)d_ws + off;
        off += (bytes + 255) & ~(size_t)255;
        return p;
    };
    int*     hist   = (int*)alloc((size_t)NREP * N * 4);
    int*     cursor = (int*)alloc((size_t)NREP * N * 4);
    int*     degc   = (int*)alloc((size_t)N * 4);
    int*     startp = (int*)alloc((size_t)(N + 1) * 4);
    float*   dinv   = (float*)alloc((size_t)N * 4);
    EdgeRec* edges  = (EdgeRec*)alloc((size_t)E * sizeof(EdgeRec));
    float*   cur0   = (float*)alloc((size_t)N * F * 4);
    float*   cur1   = (float*)alloc((size_t)N * F * 4);
    float*   update = (float*)alloc((size_t)N * F * 4);
    (void)ws_size;

    hipMemsetAsync(hist, 0, (size_t)NREP * N * 4, stream);

    const int nb_edge = (E + 256 * EPT - 1) / (256 * EPT);   // same geometry for deg+bucket
    deg_kernel<<<nb_edge, 256, 0, stream>>>(col, hist, E, N);
    sumdinv_kernel<<<(N + 255) / 256, 256, 0, stream>>>(hist, degc, dinv, N);
    scan_kernel<<<1, 1024, 0, stream>>>(degc, startp, N);
    seed_kernel<<<(N + 255) / 256, 256, 0, stream>>>(hist, startp, cursor, N);
    bucket_kernel<<<nb_edge, 256, 0, stream>>>(row, col, dinv, cursor, edges, E, N);

    float* bufs[2] = {cur0, cur1};
    for (int l = 0; l < L; ++l) {
        const float* cin = (l == 0) ? x : bufs[(l - 1) & 1];
        float* cout = bufs[l & 1];
        layer_kernel<<<(N * 64 + 255) / 256, 256, 0, stream>>>(
            cin, cout, update, startp, edges, kv, l, (l == 0) ? 1 : 0, N);
    }

    final_kernel<<<(N + TM - 1) / TM, 256, 0, stream>>>(x, update, W, b, wt, out, N);
}

// Round 6
// 248.564 us; speedup vs baseline: 17.2678x; 1.1958x over previous
//
#include <hip/hip_runtime.h>
#include <stdint.h>

#define F 128
#define NREP 8          // cursor/histogram replicas (contention /8)
#define EPT 4           // edges per thread in histogram/bucket

struct EdgeRec { int src; float norm; };

// fp16 row helpers: 4 halves packed in 8 bytes (one float2)
union H4 { float2 f2; _Float16 h[4]; };

__device__ __forceinline__ float4 load_h4(const _Float16* rowp, int li) {
    H4 u; u.f2 = ((const float2*)rowp)[li];
    return make_float4((float)u.h[0], (float)u.h[1], (float)u.h[2], (float)u.h[3]);
}
__device__ __forceinline__ void store_h4(_Float16* rowp, int li, float4 v) {
    H4 u;
    u.h[0] = (_Float16)v.x; u.h[1] = (_Float16)v.y;
    u.h[2] = (_Float16)v.z; u.h[3] = (_Float16)v.w;
    ((float2*)rowp)[li] = u.f2;
}

// ---- 0. x (fp32) -> xh (fp16) ----
__global__ void convert_kernel(const float* __restrict__ x, _Float16* __restrict__ xh,
                               int total4) {
    int i = blockIdx.x * blockDim.x + threadIdx.x;
    if (i < total4) {
        float4 v = ((const float4*)x)[i];
        H4 u;
        u.h[0] = (_Float16)v.x; u.h[1] = (_Float16)v.y;
        u.h[2] = (_Float16)v.z; u.h[3] = (_Float16)v.w;
        ((float2*)xh)[i] = u.f2;
    }
}

// ---- 1. replicated in-degree histogram over col ----
__global__ void deg_kernel(const int* __restrict__ col, int* __restrict__ hist,
                           int E, int N) {
    int rep = blockIdx.x & (NREP - 1);
    int e0 = (blockIdx.x * blockDim.x + threadIdx.x) * EPT;
    int* h = hist + (size_t)rep * N;
#pragma unroll
    for (int u = 0; u < EPT; ++u) {
        int e = e0 + u;
        if (e < E) atomicAdd(&h[col[e]], 1);
    }
}

// ---- 2. degc = sum over replicas; dinv = rsqrt(max(deg,1)) ----
__global__ void sumdinv_kernel(const int* __restrict__ hist, int* __restrict__ degc,
                               float* __restrict__ dinv, int N) {
    int n = blockIdx.x * blockDim.x + threadIdx.x;
    if (n < N) {
        int d = 0;
#pragma unroll
        for (int r = 0; r < NREP; ++r) d += hist[(size_t)r * N + n];
        degc[n] = d;
        if (d < 1) d = 1;
        dinv[n] = rsqrtf((float)d);
    }
}

// ---- 3. exclusive scan of degc -> start[0..N]  (proven) ----
__global__ void scan_kernel(const int* __restrict__ deg, int* __restrict__ start, int N) {
    __shared__ int sm[1024];
    __shared__ int carry_s;
    int tid = threadIdx.x;
    if (tid == 0) carry_s = 0;
    __syncthreads();
    for (int base = 0; base < N; base += 1024) {
        int i = base + tid;
        int v = (i < N) ? deg[i] : 0;
        int val = v;
        sm[tid] = val;
        __syncthreads();
        for (int off = 1; off < 1024; off <<= 1) {
            int t = 0;
            if (tid >= off) t = sm[tid - off];
            __syncthreads();
            val += t;
            sm[tid] = val;
            __syncthreads();
        }
        int carry = carry_s;
        if (i < N) start[i] = carry + val - v;   // exclusive
        __syncthreads();
        if (tid == 1023) carry_s = carry + val;
        __syncthreads();
    }
    if (tid == 0) start[N] = carry_s;
}

// ---- 4. seed cursor[r][c] = start[c] + prefix_r(hist[.][c]) ----
__global__ void seed_kernel(const int* __restrict__ hist, const int* __restrict__ start,
                            int* __restrict__ cursor, int N) {
    int n = blockIdx.x * blockDim.x + threadIdx.x;
    if (n < N) {
        int run = start[n];
#pragma unroll
        for (int r = 0; r < NREP; ++r) {
            cursor[(size_t)r * N + n] = run;
            run += hist[(size_t)r * N + n];
        }
    }
}

// ---- 5. bucket scatter with pre-seeded replicated cursors ----
__global__ void bucket_kernel(const int* __restrict__ row, const int* __restrict__ col,
                              const float* __restrict__ dinv,
                              int* __restrict__ cursor, EdgeRec* __restrict__ edges,
                              int E, int N) {
    int rep = blockIdx.x & (NREP - 1);
    int e0 = (blockIdx.x * blockDim.x + threadIdx.x) * EPT;
    int* cur = cursor + (size_t)rep * N;
    int cs[EPT], rs[EPT], pos[EPT];
    float nm[EPT];
#pragma unroll
    for (int u = 0; u < EPT; ++u) {
        int e = e0 + u;
        if (e < E) { cs[u] = col[e]; rs[u] = row[e]; }
    }
#pragma unroll
    for (int u = 0; u < EPT; ++u) {
        int e = e0 + u;
        if (e < E) {
            nm[u]  = dinv[rs[u]] * dinv[cs[u]];
            pos[u] = atomicAdd(&cur[cs[u]], 1);
        }
    }
#pragma unroll
    for (int u = 0; u < EPT; ++u) {
        int e = e0 + u;
        if (e < E) {
            EdgeRec rec; rec.src = rs[u]; rec.norm = nm[u];
            edges[pos[u]] = rec;
        }
    }
}

// ---- 6. one layer (fp16 cur): wave per node, half-wave gathers ----
// lanes 0-31 even staged edges, 32-63 odd; lane li covers cols 4*li..4*li+3.
// Gather load = 8 B/lane (4 halves); row = 32 lanes x 8 B = 256 B, L2-resident.
__global__ __launch_bounds__(256) void layer_kernel(
        const _Float16* __restrict__ cin, _Float16* __restrict__ cout,
        const int* __restrict__ start, const EdgeRec* __restrict__ edges, int N) {
    int node = (blockIdx.x * blockDim.x + threadIdx.x) >> 6;
    int lane = threadIdx.x & 63;
    if (node >= N) return;
    int half = lane >> 5;
    int li   = lane & 31;
    int s = start[node], t = start[node + 1];

    float4 a[8];
#pragma unroll
    for (int u = 0; u < 8; ++u) a[u] = make_float4(0.f, 0.f, 0.f, 0.f);

    for (int base = s; base < t; base += 64) {
        int cnt = t - base; if (cnt > 64) cnt = 64;
        EdgeRec rec = edges[base + (lane < cnt ? lane : 0)];  // coalesced staging
        int j = 0;
        for (; j + 16 <= cnt; j += 16) {
#pragma unroll
            for (int u = 0; u < 8; ++u) {
                int idx = j + 2 * u + half;
                int   s_ = __shfl(rec.src,  idx, 64);
                float n_ = __shfl(rec.norm, idx, 64);
                float4 v = load_h4(cin + (size_t)s_ * F, li);
                a[u].x += n_ * v.x; a[u].y += n_ * v.y;
                a[u].z += n_ * v.z; a[u].w += n_ * v.w;
            }
        }
        for (; j < cnt; j += 2) {
            int idx = j + half;
            int ic  = idx < cnt ? idx : j;
            int   s_ = __shfl(rec.src,  ic, 64);
            float n_ = __shfl(rec.norm, ic, 64);
            if (idx >= cnt) n_ = 0.f;
            float4 v = load_h4(cin + (size_t)s_ * F, li);
            a[0].x += n_ * v.x; a[0].y += n_ * v.y;
            a[0].z += n_ * v.z; a[0].w += n_ * v.w;
        }
    }
    float4 acc;
    acc.x = ((a[0].x+a[1].x)+(a[2].x+a[3].x)) + ((a[4].x+a[5].x)+(a[6].x+a[7].x));
    acc.y = ((a[0].y+a[1].y)+(a[2].y+a[3].y)) + ((a[4].y+a[5].y)+(a[6].y+a[7].y));
    acc.z = ((a[0].z+a[1].z)+(a[2].z+a[3].z)) + ((a[4].z+a[5].z)+(a[6].z+a[7].z));
    acc.w = ((a[0].w+a[1].w)+(a[2].w+a[3].w)) + ((a[4].w+a[5].w)+(a[6].w+a[7].w));
    acc.x += __shfl_xor(acc.x, 32, 64);
    acc.y += __shfl_xor(acc.y, 32, 64);
    acc.z += __shfl_xor(acc.z, 32, 64);
    acc.w += __shfl_xor(acc.w, 32, 64);

    if (half == 0) {
        float4 c = load_h4(cin + (size_t)node * F, li);
        float4 nc = make_float4(c.x - acc.x, c.y - acc.y, c.z - acc.z, c.w - acc.w);
        store_h4(cout + (size_t)node * F, li, nc);
    }
}

// ---- 7. epilogue: update = sum_l tanh(k_l)*cur_l (on the fly);
//          h = c*update + (1-c)*x; out = relu(h @ W^T + b) ----
#define TM 32
#define KC 32
__global__ __launch_bounds__(256) void final_kernel(
        const float* __restrict__ x, const _Float16* __restrict__ curh, // L slots, stride N*F
        const float* __restrict__ W, const float* __restrict__ bias,
        const float* __restrict__ kv, const float* __restrict__ wt,
        float* __restrict__ out, int N, int L) {
    __shared__ float hs[TM * F];
    __shared__ float Wl[KC * 129];
    int tid  = threadIdx.x;
    int row0 = blockIdx.x * TM;
    float cst  = 1.f / (1.f + __expf(-wt[0]));
    float cst1 = 1.f - cst;
    float t[16];
    for (int l = 0; l < L; ++l) t[l] = tanhf(kv[l]);
    const size_t NF = (size_t)N * F;

    // stage blended h tile: thread handles one 4-col quad of one row
    for (int j = tid; j < TM * 32; j += 256) {
        int r = j >> 5, q = j & 31;
        int gr = row0 + r;
        float4 hv = make_float4(0.f, 0.f, 0.f, 0.f);
        if (gr < N) {
            float4 xv = ((const float4*)(x + (size_t)gr * F))[q];
            float4 sum = make_float4(0.f, 0.f, 0.f, 0.f);
            for (int l = 0; l < L; ++l) {
                float4 cv = load_h4(curh + (size_t)l * NF + (size_t)gr * F, q);
                sum.x += t[l] * cv.x; sum.y += t[l] * cv.y;
                sum.z += t[l] * cv.z; sum.w += t[l] * cv.w;
            }
            hv.x = cst * sum.x + cst1 * xv.x;
            hv.y = cst * sum.y + cst1 * xv.y;
            hv.z = cst * sum.z + cst1 * xv.z;
            hv.w = cst * sum.w + cst1 * xv.w;
        }
        ((float4*)hs)[j & 31 | (j >> 5) << 5] = hv;   // hs[r*F..] as float4: index r*32+q
    }

    int c  = tid & 127;
    int rg = tid >> 7;
    float acc[16];
#pragma unroll
    for (int i = 0; i < 16; ++i) acc[i] = 0.f;
    for (int kc = 0; kc < F; kc += KC) {
        __syncthreads();
        for (int j = tid; j < KC * F; j += 256) {
            int c2 = j >> 5, kk = j & 31;
            Wl[kk * 129 + c2] = W[(size_t)c2 * F + kc + kk];
        }
        __syncthreads();
#pragma unroll 8
        for (int kk = 0; kk < KC; ++kk) {
            float w = Wl[kk * 129 + c];
#pragma unroll
            for (int r = 0; r < 16; ++r)
                acc[r] += hs[(rg * 16 + r) * F + kc + kk] * w;
        }
    }
    float bv = bias[c];
#pragma unroll
    for (int r = 0; r < 16; ++r) {
        int gr = row0 + rg * 16 + r;
        if (gr < N) {
            float v = acc[r] + bv;
            out[(size_t)gr * F + c] = v > 0.f ? v : 0.f;
        }
    }
}

extern "C" void kernel_launch(void* const* d_in, const int* in_sizes, int n_in,
                              void* d_out, int out_size, void* d_ws, size_t ws_size,
                              hipStream_t stream) {
    const float* x   = (const float*)d_in[0];
    const int*   ei  = (const int*)d_in[1];
    const float* kv  = (const float*)d_in[2];
    const float* wt  = (const float*)d_in[3];
    const float* W   = (const float*)d_in[4];
    const float* b   = (const float*)d_in[5];
    float* out = (float*)d_out;

    const int E = in_sizes[1] / 2;
    const int N = in_sizes[0] / F;
    const int L = in_sizes[2];
    const int* row = ei;           // edge_index[0]
    const int* col = ei + E;       // edge_index[1]
    const size_t NF = (size_t)N * F;

    size_t off = 0;
    auto alloc = [&](size_t bytes) {
        void* p = (char*)d_ws + off;
        off += (bytes + 255) & ~(size_t)255;
        return p;
    };
    int*      hist   = (int*)alloc((size_t)NREP * N * 4);
    int*      cursor = (int*)alloc((size_t)NREP * N * 4);
    int*      degc   = (int*)alloc((size_t)N * 4);
    int*      startp = (int*)alloc((size_t)(N + 1) * 4);
    float*    dinv   = (float*)alloc((size_t)N * 4);
    EdgeRec*  edges  = (EdgeRec*)alloc((size_t)E * sizeof(EdgeRec));
    _Float16* xh     = (_Float16*)alloc(NF * 2);
    _Float16* curh   = (_Float16*)alloc((size_t)L * NF * 2);   // L fp16 slots
    (void)ws_size;

    hipMemsetAsync(hist, 0, (size_t)NREP * N * 4, stream);

    convert_kernel<<<(int)((NF / 4 + 255) / 256), 256, 0, stream>>>(x, xh, (int)(NF / 4));

    const int nb_edge = (E + 256 * EPT - 1) / (256 * EPT);   // same geometry deg+bucket
    deg_kernel<<<nb_edge, 256, 0, stream>>>(col, hist, E, N);
    sumdinv_kernel<<<(N + 255) / 256, 256, 0, stream>>>(hist, degc, dinv, N);
    scan_kernel<<<1, 1024, 0, stream>>>(degc, startp, N);
    seed_kernel<<<(N + 255) / 256, 256, 0, stream>>>(hist, startp, cursor, N);
    bucket_kernel<<<nb_edge, 256, 0, stream>>>(row, col, dinv, cursor, edges, E, N);

    for (int l = 0; l < L; ++l) {
        const _Float16* cin = (l == 0) ? xh : curh + (size_t)(l - 1) * NF;
        _Float16* cout = curh + (size_t)l * NF;
        layer_kernel<<<(N * 64 + 255) / 256, 256, 0, stream>>>(cin, cout, startp, edges, N);
    }

    final_kernel<<<(N + TM - 1) / TM, 256, 0, stream>>>(x, curh, W, b, kv, wt, out, N, L);
}

// Round 7
// 239.846 us; speedup vs baseline: 17.8955x; 1.0363x over previous
//
#include <hip/hip_runtime.h>
#include <stdint.h>

#define F 128
#define NREP 8          // cursor/histogram replicas (contention /8)
#define EPT 4           // edges per thread in histogram/bucket

struct EdgeRec { int src; float norm; };

union H4 { float2 f2; _Float16 h[4]; };
union H8 { float4 f4; _Float16 h[8]; };

// ---- 1. fused: x(fp32)->xh(fp16) + replicated in-degree histogram ----
__global__ void convdeg_kernel(const float* __restrict__ x, _Float16* __restrict__ xh,
                               int total4, const int* __restrict__ col,
                               int* __restrict__ hist, int E, int N) {
    int rep = blockIdx.x & (NREP - 1);
    int i0 = (blockIdx.x * blockDim.x + threadIdx.x) * EPT;
    int* h = hist + (size_t)rep * N;
#pragma unroll
    for (int u = 0; u < EPT; ++u) {
        int e = i0 + u;
        if (e < E) atomicAdd(&h[col[e]], 1);
    }
#pragma unroll
    for (int u = 0; u < EPT; ++u) {
        int i = i0 + u;
        if (i < total4) {
            float4 v = ((const float4*)x)[i];
            H4 p;
            p.h[0] = (_Float16)v.x; p.h[1] = (_Float16)v.y;
            p.h[2] = (_Float16)v.z; p.h[3] = (_Float16)v.w;
            ((float2*)xh)[i] = p.f2;
        }
    }
}

// ---- 2. fused node-side: deg-sum + dinv + exclusive scan + cursor seed ----
// single block, 1024 threads, wave-shuffle scan (4 barriers per 1024-chunk)
__global__ __launch_bounds__(1024) void nodeproc_kernel(
        const int* __restrict__ hist, float* __restrict__ dinv,
        int* __restrict__ start, int* __restrict__ cursor, int N) {
    __shared__ int wsum[16];
    __shared__ int carry_s;
    int tid = threadIdx.x, lane = tid & 63, wid = tid >> 6;
    if (tid == 0) carry_s = 0;
    __syncthreads();
    for (int base = 0; base < N; base += 1024) {
        int i = base + tid;
        int h[NREP];
        int v = 0;
        if (i < N) {
#pragma unroll
            for (int r = 0; r < NREP; ++r) { h[r] = hist[(size_t)r * N + i]; v += h[r]; }
            int d = v < 1 ? 1 : v;
            dinv[i] = rsqrtf((float)d);
        }
        int inc = v;                              // wave-inclusive scan
        for (int off = 1; off < 64; off <<= 1) {
            int t = __shfl_up(inc, off, 64);
            if (lane >= off) inc += t;
        }
        if (lane == 63) wsum[wid] = inc;
        __syncthreads();
        if (wid == 0) {
            int wv = (lane < 16) ? wsum[lane] : 0;
            for (int off = 1; off < 16; off <<= 1) {
                int t = __shfl_up(wv, off, 64);
                if (lane >= off) wv += t;
            }
            if (lane < 16) wsum[lane] = wv;       // inclusive wave totals
        }
        __syncthreads();
        int carry = carry_s;
        int woff = (wid > 0) ? wsum[wid - 1] : 0;
        if (i < N) {
            int st = carry + woff + inc - v;      // exclusive prefix
            start[i] = st;
            int run = st;
#pragma unroll
            for (int r = 0; r < NREP; ++r) { cursor[(size_t)r * N + i] = run; run += h[r]; }
        }
        __syncthreads();
        if (tid == 0) carry_s = carry + wsum[15];
        __syncthreads();
    }
    if (tid == 0) start[N] = carry_s;
}

// ---- 3. bucket scatter with pre-seeded replicated cursors (proven) ----
__global__ void bucket_kernel(const int* __restrict__ row, const int* __restrict__ col,
                              const float* __restrict__ dinv,
                              int* __restrict__ cursor, EdgeRec* __restrict__ edges,
                              int E, int N) {
    int rep = blockIdx.x & (NREP - 1);
    int e0 = (blockIdx.x * blockDim.x + threadIdx.x) * EPT;
    int* cur = cursor + (size_t)rep * N;
    int cs[EPT], rs[EPT], pos[EPT];
    float nm[EPT];
#pragma unroll
    for (int u = 0; u < EPT; ++u) {
        int e = e0 + u;
        if (e < E) { cs[u] = col[e]; rs[u] = row[e]; }
    }
#pragma unroll
    for (int u = 0; u < EPT; ++u) {
        int e = e0 + u;
        if (e < E) {
            nm[u]  = dinv[rs[u]] * dinv[cs[u]];
            pos[u] = atomicAdd(&cur[cs[u]], 1);
        }
    }
#pragma unroll
    for (int u = 0; u < EPT; ++u) {
        int e = e0 + u;
        if (e < E) {
            EdgeRec rec; rec.src = rs[u]; rec.norm = nm[u];
            edges[pos[u]] = rec;
        }
    }
}

// ---- 4. one layer (fp16): quarter-wave float4 gathers ----
// quarter q (16 lanes) handles staged edges j+q, j+4+q, ...; lane li covers
// halves 8*li..8*li+7; one dwordx4 load = half the row per lane pair-of-quads.
__global__ __launch_bounds__(256) void layer_kernel(
        const _Float16* __restrict__ cin, _Float16* __restrict__ cout,
        const int* __restrict__ start, const EdgeRec* __restrict__ edges, int N) {
    int node = (blockIdx.x * blockDim.x + threadIdx.x) >> 6;
    int lane = threadIdx.x & 63;
    if (node >= N) return;
    int q  = lane >> 4;        // quarter 0..3
    int li = lane & 15;        // lane-in-quarter
    int s = start[node], t = start[node + 1];

    float a[8];
#pragma unroll
    for (int i = 0; i < 8; ++i) a[i] = 0.f;

    for (int base = s; base < t; base += 64) {
        int cnt = t - base; if (cnt > 64) cnt = 64;
        EdgeRec rec = edges[base + (lane < cnt ? lane : 0)];   // coalesced staging
        int j = 0;
        for (; j + 32 <= cnt; j += 32) {
#pragma unroll
            for (int u = 0; u < 8; ++u) {
                int idx = j + 4 * u + q;
                int   s_ = __shfl(rec.src,  idx, 64);
                float n_ = __shfl(rec.norm, idx, 64);
                H8 v; v.f4 = ((const float4*)(cin + (size_t)s_ * F))[li];
#pragma unroll
                for (int i = 0; i < 8; ++i) a[i] += n_ * (float)v.h[i];
            }
        }
        for (; j < cnt; j += 4) {
            int idx = j + q;
            int ic  = idx < cnt ? idx : j;
            int   s_ = __shfl(rec.src,  ic, 64);
            float n_ = __shfl(rec.norm, ic, 64);
            if (idx >= cnt) n_ = 0.f;
            H8 v; v.f4 = ((const float4*)(cin + (size_t)s_ * F))[li];
#pragma unroll
            for (int i = 0; i < 8; ++i) a[i] += n_ * (float)v.h[i];
        }
    }
    // combine quarters (lanes li, li+16, li+32, li+48 hold same columns)
#pragma unroll
    for (int i = 0; i < 8; ++i) {
        a[i] += __shfl_xor(a[i], 16, 64);
        a[i] += __shfl_xor(a[i], 32, 64);
    }
    if (q == 0) {
        H8 c; c.f4 = ((const float4*)(cin + (size_t)node * F))[li];
        H8 o;
#pragma unroll
        for (int i = 0; i < 8; ++i) o.h[i] = (_Float16)((float)c.h[i] - a[i]);
        ((float4*)(cout + (size_t)node * F))[li] = o.f4;
    }
}

// ---- 5. epilogue: update = sum_l tanh(k_l)*cur_l; h = c*upd+(1-c)*x;
//          out = relu(h @ W^T + b) ----
#define TM 32
#define KC 32
__global__ __launch_bounds__(256) void final_kernel(
        const float* __restrict__ x, const _Float16* __restrict__ curh,
        const float* __restrict__ W, const float* __restrict__ bias,
        const float* __restrict__ kv, const float* __restrict__ wt,
        float* __restrict__ out, int N, int L) {
    __shared__ float hs[TM * F];
    __shared__ float Wl[KC * 129];
    int tid  = threadIdx.x;
    int row0 = blockIdx.x * TM;
    float cst  = 1.f / (1.f + __expf(-wt[0]));
    float cst1 = 1.f - cst;
    float t[16];
    for (int l = 0; l < L; ++l) t[l] = tanhf(kv[l]);
    const size_t NF = (size_t)N * F;

    for (int j = tid; j < TM * 32; j += 256) {
        int r = j >> 5, qd = j & 31;
        int gr = row0 + r;
        float4 hv = make_float4(0.f, 0.f, 0.f, 0.f);
        if (gr < N) {
            float4 xv = ((const float4*)(x + (size_t)gr * F))[qd];
            float4 sum = make_float4(0.f, 0.f, 0.f, 0.f);
            for (int l = 0; l < L; ++l) {
                H4 u; u.f2 = ((const float2*)(curh + (size_t)l * NF + (size_t)gr * F))[qd];
                sum.x += t[l] * (float)u.h[0]; sum.y += t[l] * (float)u.h[1];
                sum.z += t[l] * (float)u.h[2]; sum.w += t[l] * (float)u.h[3];
            }
            hv.x = cst * sum.x + cst1 * xv.x;
            hv.y = cst * sum.y + cst1 * xv.y;
            hv.z = cst * sum.z + cst1 * xv.z;
            hv.w = cst * sum.w + cst1 * xv.w;
        }
        ((float4*)hs)[j] = hv;
    }

    int c  = tid & 127;
    int rg = tid >> 7;
    float acc[16];
#pragma unroll
    for (int i = 0; i < 16; ++i) acc[i] = 0.f;
    for (int kc = 0; kc < F; kc += KC) {
        __syncthreads();
        for (int j = tid; j < KC * F; j += 256) {
            int c2 = j >> 5, kk = j & 31;
            Wl[kk * 129 + c2] = W[(size_t)c2 * F + kc + kk];
        }
        __syncthreads();
#pragma unroll 8
        for (int kk = 0; kk < KC; ++kk) {
            float w = Wl[kk * 129 + c];
#pragma unroll
            for (int r = 0; r < 16; ++r)
                acc[r] += hs[(rg * 16 + r) * F + kc + kk] * w;
        }
    }
    float bv = bias[c];
#pragma unroll
    for (int r = 0; r < 16; ++r) {
        int gr = row0 + rg * 16 + r;
        if (gr < N) {
            float v = acc[r] + bv;
            out[(size_t)gr * F + c] = v > 0.f ? v : 0.f;
        }
    }
}

extern "C" void kernel_launch(void* const* d_in, const int* in_sizes, int n_in,
                              void* d_out, int out_size, void* d_ws, size_t ws_size,
                              hipStream_t stream) {
    const float* x   = (const float*)d_in[0];
    const int*   ei  = (const int*)d_in[1];
    const float* kv  = (const float*)d_in[2];
    const float* wt  = (const float*)d_in[3];
    const float* W   = (const float*)d_in[4];
    const float* b   = (const float*)d_in[5];
    float* out = (float*)d_out;

    const int E = in_sizes[1] / 2;
    const int N = in_sizes[0] / F;
    const int L = in_sizes[2];
    const int* row = ei;           // edge_index[0]
    const int* col = ei + E;       // edge_index[1]
    const size_t NF = (size_t)N * F;
    const int total4 = (int)(NF / 4);

    size_t off = 0;
    auto alloc = [&](size_t bytes) {
        void* p = (char*)d_ws + off;
        off += (bytes + 255) & ~(size_t)255;
        return p;
    };
    int*      hist   = (int*)alloc((size_t)NREP * N * 4);
    int*      cursor = (int*)alloc((size_t)NREP * N * 4);
    int*      startp = (int*)alloc((size_t)(N + 1) * 4);
    float*    dinv   = (float*)alloc((size_t)N * 4);
    EdgeRec*  edges  = (EdgeRec*)alloc((size_t)E * sizeof(EdgeRec));
    _Float16* xh     = (_Float16*)alloc(NF * 2);
    _Float16* curh   = (_Float16*)alloc((size_t)L * NF * 2);
    (void)ws_size;

    hipMemsetAsync(hist, 0, (size_t)NREP * N * 4, stream);

    const int work = (E > total4 ? E : total4);
    const int nb_edge = (work + 256 * EPT - 1) / (256 * EPT);   // same geometry for bucket
    convdeg_kernel<<<nb_edge, 256, 0, stream>>>(x, xh, total4, col, hist, E, N);
    nodeproc_kernel<<<1, 1024, 0, stream>>>(hist, dinv, startp, cursor, N);
    bucket_kernel<<<nb_edge, 256, 0, stream>>>(row, col, dinv, cursor, edges, E, N);

    for (int l = 0; l < L; ++l) {
        const _Float16* cin = (l == 0) ? xh : curh + (size_t)(l - 1) * NF;
        _Float16* cout = curh + (size_t)l * NF;
        layer_kernel<<<(N * 64 + 255) / 256, 256, 0, stream>>>(cin, cout, startp, edges, N);
    }

    final_kernel<<<(N + TM - 1) / TM, 256, 0, stream>>>(x, curh, W, b, kv, wt, out, N, L);
}